// Round 11
// baseline (302.743 us; speedup 1.0000x reference)
//
#include <hip/hip_runtime.h>
#include <math.h>

#define Bn 16
#define Lq 384
#define Hn 12
#define Dm 768
#define DH 64
#define QT2 16
#define NEGV (-1e18f)
#define SPADU 404   // e/P row stride in ushort
#define ECAP 32     // per-row pair-entry capacity (data max ~8)

typedef __attribute__((ext_vector_type(4))) float f32x4;
typedef __attribute__((ext_vector_type(8))) __bf16 bf16x8;
typedef __attribute__((ext_vector_type(4))) __bf16 bf16x4;
typedef unsigned short ushort_t;
typedef unsigned int uint_t;
typedef unsigned long long ull_t;

__device__ __forceinline__ ushort_t f2b(float f) {
  return __builtin_bit_cast(ushort_t, (__bf16)f);   // native RNE cvt
}
__device__ __forceinline__ float b2f(ushort_t u) {
  return __uint_as_float(((unsigned int)u) << 16);
}
__device__ __forceinline__ bf16x8 cvt8(float4 a, float4 b) {
  bf16x8 r;
  r[0] = (__bf16)a.x; r[1] = (__bf16)a.y; r[2] = (__bf16)a.z; r[3] = (__bf16)a.w;
  r[4] = (__bf16)b.x; r[5] = (__bf16)b.y; r[6] = (__bf16)b.z; r[7] = (__bf16)b.w;
  return r;
}

// ---------------- merged prologue:
// [0,24): Age/Agr | [24,2328): weight transposes | [2328,2352): win scatter
// [2352,3888): mask bitmask rows (4 rows/block, 1 per wave)
__global__ __launch_bounds__(256) void k_prep(
    const float* __restrict__ Wge, const float* __restrict__ Wgr,
    const float* __restrict__ Vg,
    float* __restrict__ Age, float* __restrict__ Agr,
    const float* __restrict__ W0, const float* __restrict__ W1,
    const float* __restrict__ W2, const float* __restrict__ W3,
    ushort_t* __restrict__ T0, ushort_t* __restrict__ T1,
    ushort_t* __restrict__ T2, ushort_t* __restrict__ T3,
    const int* __restrict__ dp, int* __restrict__ win,
    const int* __restrict__ mask, ull_t* __restrict__ mbits)
{
  __shared__ float vg[DH];
  __shared__ float t[32][33];
  int blk = blockIdx.x;
  if (blk < 24) {
    int which = blk / Hn;
    int h = blk % Hn;
    const float* Wsrc = which ? Wgr : Wge;
    float* dst = which ? Agr : Age;
    if (threadIdx.x < DH) vg[threadIdx.x] = Vg[h*DH + threadIdx.x];
    __syncthreads();
    for (int d = threadIdx.x; d < Dm; d += 256) {
      const float* wrow = Wsrc + (size_t)d*Dm + h*DH;
      float s = 0.f;
      #pragma unroll 8
      for (int j = 0; j < DH; ++j) s = fmaf(wrow[j], vg[j], s);
      dst[h*Dm + d] = s;
    }
  } else if (blk < 24 + 2304) {
    int b2 = blk - 24;
    int z = b2 / 576, rem = b2 % 576;
    const float* W = (z == 0) ? W0 : (z == 1) ? W1 : (z == 2) ? W2 : W3;
    ushort_t* WT = (z == 0) ? T0 : (z == 1) ? T1 : (z == 2) ? T2 : T3;
    int k0 = (rem / 24)*32, n0 = (rem % 24)*32;
    int tx = threadIdx.x & 31, ty = threadIdx.x >> 5;
    #pragma unroll
    for (int r = 0; r < 4; ++r)
      t[ty + r*8][tx] = W[(size_t)(k0 + ty + r*8)*Dm + n0 + tx];
    __syncthreads();
    #pragma unroll
    for (int r = 0; r < 4; ++r)
      WT[(size_t)(n0 + ty + r*8)*Dm + k0 + tx] = f2b(t[tx][ty + r*8]);
  } else if (blk < 2352) {
    int i = (blk - 2328)*256 + threadIdx.x;
    int b = i / Lq, l = i % Lq;
    int p0 = dp[(size_t)(b*2+0)*Lq + l];
    int p1 = dp[(size_t)(b*2+1)*Lq + l];
    atomicMax(&win[(size_t)b*Lq*Lq + (size_t)p0*Lq + p1], l);
  } else {
    int rr = blk - 2352;                 // 0..1535
    int lane = threadIdx.x & 63, wave = threadIdx.x >> 6;
    int gi = rr*4 + wave;                // global row 0..6143
    const int* mrow = mask + (size_t)gi*Lq;
    ull_t w0 = __ballot(mrow[lane]        != 0);
    ull_t w1 = __ballot(mrow[lane + 64]   != 0);
    ull_t w2 = __ballot(mrow[lane + 128]  != 0);
    ull_t w3 = __ballot(mrow[lane + 192]  != 0);
    ull_t w4 = __ballot(mrow[lane + 256]  != 0);
    ull_t w5 = __ballot(mrow[lane + 320]  != 0);
    if (lane == 0) {
      ull_t* out = mbits + (size_t)gi*6;
      out[0] = w0; out[1] = w1; out[2] = w2;
      out[3] = w3; out[4] = w4; out[5] = w5;
    }
  }
}

// ---------------- collect sparse pair entries per row (win + win^T nonzeros)
__global__ __launch_bounds__(256) void k_collect(
    const int* __restrict__ win, uint_t* __restrict__ ent,
    int* __restrict__ rowcnt)
{
  __shared__ int tB[32][33];
  int b = blockIdx.z;
  int i0 = blockIdx.x*32, j0 = blockIdx.y*32;
  const int* wb = win + (size_t)b*Lq*Lq;
  int tx = threadIdx.x & 31, ty = threadIdx.x >> 5;
  #pragma unroll
  for (int rr = 0; rr < 4; ++rr) {
    int r = ty + rr*8;
    tB[r][tx] = wb[(size_t)(j0+r)*Lq + i0 + tx];
  }
  __syncthreads();
  #pragma unroll
  for (int rr = 0; rr < 4; ++rr) {
    int ti = ty + rr*8;
    int i = i0 + ti, j = j0 + tx;
    int l1 = wb[(size_t)i*Lq + j];
    int l2 = tB[tx][ti];
    if (l1 >= 0 || l2 >= 0) {
      int slot = atomicAdd(&rowcnt[(size_t)b*Lq + i], 1);
      if (slot < ECAP)
        ent[((size_t)b*Lq + i)*ECAP + slot] =
            (uint_t)j | ((uint_t)(l1 + 1) << 9) | ((uint_t)(l2 + 1) << 19);
    }
  }
}

// ---------------- g (tanh gate) and rlog; 4 l-rows per block, wave per row
__global__ __launch_bounds__(256) void k_grlog(
    const float* __restrict__ values, const float* __restrict__ relations,
    const int* __restrict__ dp, const int* __restrict__ rel_mask,
    const float* __restrict__ Age, const float* __restrict__ Agr,
    const float* __restrict__ Vr,
    float* __restrict__ g, float* __restrict__ rlog)
{
  int blk = blockIdx.x;
  int b = blk / (Lq/4), l0 = (blk % (Lq/4))*4;
  int tid = threadIdx.x, lane = tid & 63, wave = tid >> 6;
  __shared__ float relrow[4][Dm], hvrow[4][Dm];
  #pragma unroll
  for (int rr = 0; rr < 4; ++rr) {
    int l = l0 + rr;
    int rm = rel_mask[(size_t)b*Lq + l];
    int idx = dp[(size_t)(b*2)*Lq + l];
    const float* vrow = values + ((size_t)b*Lq + idx)*Dm;
    const float* rrow = relations + ((size_t)b*Lq + l)*Dm;
    for (int d = tid; d < Dm; d += 256) {
      relrow[rr][d] = rm ? 0.f : rrow[d];
      hvrow[rr][d]  = (rm || l == 0) ? 0.f : vrow[d];
    }
  }
  __syncthreads();
  int l = l0 + wave;
  for (int h = 0; h < Hn; ++h) {
    float p = 0.f;
    #pragma unroll
    for (int k = 0; k < Dm/64; ++k) {
      int d = lane + 64*k;
      p = fmaf(hvrow[wave][d], Age[h*Dm + d],
          fmaf(relrow[wave][d], Agr[h*Dm + d], p));
    }
    #pragma unroll
    for (int o = 32; o > 0; o >>= 1) p += __shfl_xor(p, o);
    if (lane == 0) g[((size_t)b*Hn + h)*Lq + l] = tanhf(p);
  }
  if (lane < Hn) {
    float s = 0.f;
    #pragma unroll 8
    for (int j = 0; j < DH; ++j)
      s = fmaf(relrow[wave][lane*DH + j], Vr[lane*DH + j], s);
    rlog[((size_t)b*Hn + lane)*Lq + l] = s;
  }
}

// ---------------- fused QKV projection GEMM, software-pipelined K-loop
// (issue loads for step k+1 before computing step k; vmcnt drain at barrier)
// blockIdx.z: 0=q (x0.125), 1=k, 2=v (transposed per-batch output)
__global__ __launch_bounds__(256, 3) void k_mmqkv(
    const float* __restrict__ Xq, const float* __restrict__ Xk,
    const float* __restrict__ Xv,
    const ushort_t* __restrict__ WqT, const ushort_t* __restrict__ WkT,
    const ushort_t* __restrict__ WvT,
    ushort_t* __restrict__ qbf, ushort_t* __restrict__ kbf,
    ushort_t* __restrict__ vTbf)
{
  __shared__ ushort_t As[128*64];
  __shared__ ushort_t Bs[128*64];

  int z = blockIdx.z;
  const float* A     = (z == 0) ? Xq : (z == 1) ? Xk : Xv;
  const ushort_t* BT = (z == 0) ? WqT : (z == 1) ? WkT : WvT;

  int bm = blockIdx.x;
  int bn = blockIdx.y;
  int m_blk = bm*128;

  int t = threadIdx.x;
  int wave = t >> 6, lane = t & 63;
  int wr = wave >> 1, wc = wave & 1;
  int lrow = lane & 15, lkg = lane >> 4;
  int sr = t >> 3, sc8 = t & 7;

  float4 fa[4][2];
  uint4 vb[4];
  auto LOAD = [&](int k0) {
    #pragma unroll
    for (int i = 0; i < 4; ++i) {
      int row = sr + i*32;
      const float* ap = A + (size_t)(m_blk + row)*Dm + k0 + sc8*8;
      fa[i][0] = *(const float4*)ap;
      fa[i][1] = *(const float4*)(ap + 4);
      vb[i] = *(const uint4*)(BT + (size_t)(bn*128 + row)*Dm + k0 + sc8*8);
    }
  };
  auto STORE = [&]() {
    #pragma unroll
    for (int i = 0; i < 4; ++i) {
      int row = sr + i*32;
      int slot = sc8 ^ (row & 7);
      *(bf16x8*)&As[row*64 + slot*8] = cvt8(fa[i][0], fa[i][1]);
      *(uint4*)&Bs[row*64 + slot*8] = vb[i];
    }
  };

  f32x4 acc[4][4];
  #pragma unroll
  for (int i = 0; i < 4; ++i)
    #pragma unroll
    for (int j = 0; j < 4; ++j) acc[i][j] = (f32x4)(0.f);

  LOAD(0);
  STORE();
  __syncthreads();

  for (int ks = 0; ks < 12; ++ks) {
    if (ks < 11) LOAD((ks + 1)*64);     // issue early, hides under MFMA below
    #pragma unroll
    for (int kk = 0; kk < 2; ++kk) {
      bf16x8 aF[4], bF[4];
      int chunk = kk*4 + lkg;
      #pragma unroll
      for (int mi = 0; mi < 4; ++mi) {
        int arow = wr*64 + mi*16 + lrow;
        aF[mi] = *(const bf16x8*)&As[arow*64 + ((chunk ^ (arow & 7)) << 3)];
        int brow = wc*64 + mi*16 + lrow;
        bF[mi] = *(const bf16x8*)&Bs[brow*64 + ((chunk ^ (brow & 7)) << 3)];
      }
      #pragma unroll
      for (int mi = 0; mi < 4; ++mi)
        #pragma unroll
        for (int ni = 0; ni < 4; ++ni)
          acc[mi][ni] = __builtin_amdgcn_mfma_f32_16x16x32_bf16(
              aF[mi], bF[ni], acc[mi][ni], 0, 0, 0);
    }
    __syncthreads();                    // all reads done (+ vmcnt drain here)
    if (ks < 11) {
      STORE();
      __syncthreads();
    }
  }

  float alpha = (z == 0) ? 0.125f : 1.f;
  #pragma unroll
  for (int mi = 0; mi < 4; ++mi) {
    #pragma unroll
    for (int ni = 0; ni < 4; ++ni) {
      f32x4 a = acc[mi][ni];
      int rit = wr*64 + mi*16 + 4*lkg;
      int cit = wc*64 + ni*16 + lrow;
      int gcol = bn*128 + cit;
      if (z < 2) {
        ushort_t* Cb = z ? kbf : qbf;
        int grow = m_blk + rit;
        #pragma unroll
        for (int r = 0; r < 4; ++r)
          Cb[(size_t)(grow + r)*Dm + gcol] = f2b(a[r]*alpha);
      } else {
        int b = bm/3;
        int rl = (bm%3)*128 + rit;
        ushort4 u;
        u.x = f2b(a[0]); u.y = f2b(a[1]); u.z = f2b(a[2]); u.w = f2b(a[3]);
        *(ushort4*)&vTbf[((size_t)b*Dm + gcol)*Lq + rl] = u;
      }
    }
  }
}

// ---------------- 64x128-tile bf16 GEMM, software-pipelined.
// MODE 0: C[M][768] f32 (grid 96,6,1).  MODE 3: batched aw (grid 6,3,16).
template<int MODE>
__global__ __launch_bounds__(256, 3) void k_mm64(
    const ushort_t* __restrict__ A, const ushort_t* __restrict__ BT,
    float* __restrict__ Cf, const int* __restrict__ mask, float alpha)
{
  __shared__ ushort_t As[64*64];    // 8KB
  __shared__ ushort_t Bs[128*64];   // 16KB

  int bm = blockIdx.x, bn = blockIdx.y, b = blockIdx.z;
  const ushort_t* Ab = (MODE == 3) ? A  + (size_t)b*Lq*Dm : A;
  const ushort_t* Bb = (MODE == 3) ? BT + (size_t)b*Lq*Dm : BT;
  int m0 = bm*64, n0 = bn*128;

  int t = threadIdx.x;
  int wave = t >> 6, lane = t & 63;
  int wr = wave >> 1, wc = wave & 1;
  int lrow = lane & 15, lkg = lane >> 4;
  int sr = t >> 3, sc8 = t & 7;

  uint4 va[2], vbr[4];
  auto LOAD = [&](int k0) {
    #pragma unroll
    for (int i = 0; i < 2; ++i) {
      int row = sr + i*32;
      va[i] = *(const uint4*)(Ab + (size_t)(m0 + row)*Dm + k0 + sc8*8);
    }
    #pragma unroll
    for (int i = 0; i < 4; ++i) {
      int row = sr + i*32;
      vbr[i] = *(const uint4*)(Bb + (size_t)(n0 + row)*Dm + k0 + sc8*8);
    }
  };
  auto STORE = [&]() {
    #pragma unroll
    for (int i = 0; i < 2; ++i) {
      int row = sr + i*32;
      *(uint4*)&As[row*64 + (sc8 ^ (row & 7))*8] = va[i];
    }
    #pragma unroll
    for (int i = 0; i < 4; ++i) {
      int row = sr + i*32;
      *(uint4*)&Bs[row*64 + (sc8 ^ (row & 7))*8] = vbr[i];
    }
  };

  f32x4 acc[2][4];
  #pragma unroll
  for (int i = 0; i < 2; ++i)
    #pragma unroll
    for (int j = 0; j < 4; ++j) acc[i][j] = (f32x4)(0.f);

  LOAD(0);
  STORE();
  __syncthreads();

  for (int ks = 0; ks < 12; ++ks) {
    if (ks < 11) LOAD((ks + 1)*64);
    #pragma unroll
    for (int kk = 0; kk < 2; ++kk) {
      bf16x8 aF[2], bF[4];
      int chunk = kk*4 + lkg;
      #pragma unroll
      for (int mi = 0; mi < 2; ++mi) {
        int arow = wr*32 + mi*16 + lrow;
        aF[mi] = *(const bf16x8*)&As[arow*64 + ((chunk ^ (arow & 7)) << 3)];
      }
      #pragma unroll
      for (int ni = 0; ni < 4; ++ni) {
        int brow = wc*64 + ni*16 + lrow;
        bF[ni] = *(const bf16x8*)&Bs[brow*64 + ((chunk ^ (brow & 7)) << 3)];
      }
      #pragma unroll
      for (int mi = 0; mi < 2; ++mi)
        #pragma unroll
        for (int ni = 0; ni < 4; ++ni)
          acc[mi][ni] = __builtin_amdgcn_mfma_f32_16x16x32_bf16(
              aF[mi], bF[ni], acc[mi][ni], 0, 0, 0);
    }
    __syncthreads();
    if (ks < 11) {
      STORE();
      __syncthreads();
    }
  }

  #pragma unroll
  for (int mi = 0; mi < 2; ++mi) {
    #pragma unroll
    for (int ni = 0; ni < 4; ++ni) {
      f32x4 a = acc[mi][ni];
      int rit = wr*32 + mi*16 + 4*lkg;
      int cit = wc*64 + ni*16 + lrow;
      if (MODE == 0) {
        int grow = m0 + rit, gcol = n0 + cit;
        #pragma unroll
        for (int r = 0; r < 4; ++r)
          Cf[(size_t)(grow + r)*Dm + gcol] = a[r]*alpha;
      } else {
        int rl = m0 + rit, cl = n0 + cit;
        const int* mb2 = mask + (size_t)b*Lq*Lq;
        float* awb = Cf + (size_t)b*Lq*Lq;
        #pragma unroll
        for (int r = 0; r < 4; ++r) {
          int m = mb2[(size_t)(rl + r)*Lq + cl];
          awb[(size_t)(rl + r)*Lq + cl] = m ? NEGV : a[r]*alpha;
        }
      }
    }
  }
}

// ---------------- fused per-(b,h,16-q-rows) attention, MFMA QK + PV
// All k-fragments loaded up front (in flight during prefetch+barrier);
// vT fragments hoisted before phase-2 barrier (complete during phase 2).
__global__ __launch_bounds__(256, 4) void k_attn3(
    const ushort_t* __restrict__ qbf, const ushort_t* __restrict__ kbf,
    const ushort_t* __restrict__ vT,
    const ull_t* __restrict__ mbits, const int* __restrict__ rowcnt,
    const uint_t* __restrict__ ent,
    const float* __restrict__ g, const float* __restrict__ rlog,
    ushort_t* __restrict__ ctxbf)
{
  __shared__ ushort_t S16[QT2][SPADU];  // 12.9KB: e (exp, masked), patched
  __shared__ ull_t mb[QT2][6];          // 768B
  __shared__ float2 rg2[Lq + 1];        // 3.1KB: (rlog, g), zero slot at 0
  __shared__ uint_t entS[QT2*ECAP];     // 2KB
  __shared__ int cntS[QT2];             // 64B
  __shared__ float pp[QT2][4];          // 256B
  __shared__ float sinvS[QT2];          // 64B

  int bid = blockIdx.x;
  int h  = bid % Hn;
  int qt = (bid / Hn) % (Lq/QT2);
  int b  = bid / (Hn * (Lq/QT2));
  int q0 = qt * QT2;
  int tid = threadIdx.x, lane = tid & 63, wave = tid >> 6;
  int lrow = lane & 15, lkg = lane >> 4;

  const float* gh = g    + ((size_t)b*Hn + h)*Lq;
  const float* rh = rlog + ((size_t)b*Hn + h)*Lq;

  // ---- q + ALL k fragments issued first (12 outstanding 16B loads) ----
  const ushort_t* qb = qbf + ((size_t)b*Lq + q0 + lrow)*Dm + h*DH + lkg*8;
  bf16x8 aF0 = *(const bf16x8*)(qb);
  bf16x8 aF1 = *(const bf16x8*)(qb + 32);
  int col0 = wave*96;
  bf16x8 bF[6][2];
  {
    const ushort_t* kb = kbf + ((size_t)b*Lq + col0 + lrow)*Dm + h*DH + lkg*8;
    #pragma unroll
    for (int tt = 0; tt < 6; ++tt) {
      bF[tt][0] = *(const bf16x8*)(kb);
      bF[tt][1] = *(const bf16x8*)(kb + 32);
      kb += 16*Dm;
    }
  }

  // ---- prefetch all phase-2 inputs into LDS ----
  if (tid < QT2*6) {
    int r = tid / 6, u = tid % 6;
    mb[r][u] = mbits[((size_t)b*Lq + q0 + r)*6 + u];
  }
  if (tid == 0) { rg2[0].x = 0.f; rg2[0].y = 0.f; }
  for (int e = tid; e < Lq; e += 256) {
    float2 v2; v2.x = rh[e]; v2.y = gh[e];
    rg2[e + 1] = v2;
  }
  #pragma unroll
  for (int e = tid; e < QT2*ECAP; e += 256)
    entS[e] = ent[((size_t)b*Lq + q0)*ECAP + e];
  if (tid < QT2) {
    int c = rowcnt[(size_t)b*Lq + q0 + tid];
    cntS[tid] = c > ECAP ? ECAP : c;
  }
  __syncthreads();   // mb visible to phase 1 (k loads drained here, parallel)

  // Phase 1: QK MFMA -> mask-zero -> exp -> reg partial sums + single e write
  {
    int w0 = col0 >> 6;
    ull_t m0[4], m1[4];
    #pragma unroll
    for (int r = 0; r < 4; ++r) {
      m0[r] = mb[4*lkg + r][w0];
      m1[r] = mb[4*lkg + r][w0 + 1];
    }
    float ps[4] = {0.f, 0.f, 0.f, 0.f};
    #pragma unroll
    for (int tt = 0; tt < 6; ++tt) {
      int col = col0 + tt*16 + lrow;
      f32x4 z = (f32x4)(0.f);
      z = __builtin_amdgcn_mfma_f32_16x16x32_bf16(aF0, bF[tt][0], z, 0, 0, 0);
      z = __builtin_amdgcn_mfma_f32_16x16x32_bf16(aF1, bF[tt][1], z, 0, 0, 0);
      bool hi = ((col0 + tt*16) >> 6) != w0;
      int sh = col & 63;
      #pragma unroll
      for (int r = 0; r < 4; ++r) {
        ull_t mw = hi ? m1[r] : m0[r];
        bool mk = (mw >> sh) & 1ull;
        float e = mk ? 0.f : __expf(z[r]);
        ps[r] += e;
        S16[4*lkg + r][col] = f2b(e);
      }
    }
    #pragma unroll
    for (int off = 1; off < 16; off <<= 1)
      #pragma unroll
      for (int r = 0; r < 4; ++r) ps[r] += __shfl_xor(ps[r], off);
    if (lrow == 0) {
      #pragma unroll
      for (int r = 0; r < 4; ++r) pp[4*lkg + r][wave] = ps[r];
    }
  }

  // ---- hoist ALL vT fragments (complete during barrier + phase 2) ----
  int dcol = h*DH + wave*16 + lrow;
  bf16x8 bv[12];
  {
    const ushort_t* vb2 = vT + ((size_t)b*Dm + dcol)*Lq + lkg*8;
    #pragma unroll
    for (int ks = 0; ks < 12; ++ks) bv[ks] = *(const bf16x8*)(vb2 + ks*32);
  }
  __syncthreads();

  // Phase 2: 16 threads — sinv per row + in-place pair patches on e
  if (tid < QT2) {
    int row = tid;
    float ssum = pp[row][0] + pp[row][1] + pp[row][2] + pp[row][3];
    float si = 1.f / ssum;
    sinvS[row] = si;
    int nun = 384;
    #pragma unroll
    for (int u = 0; u < 6; ++u) nun -= (int)__popcll(mb[row][u]);
    int cnt = cntS[row];
    const uint_t* erow = &entS[row*ECAP];
    float rext = 0.f;
    for (int e = 0; e < cnt; ++e) {
      uint_t en = erow[e];
      int j = en & 511;
      if ((mb[row][j >> 6] >> (j & 63)) & 1ull) continue;
      float rel = rg2[(en >> 9) & 1023].x + rg2[en >> 19].x;
      rext += __expf(rel) - 1.f;
    }
    float sr = ssum / ((float)nun + rext);   // ssum * rinv
    for (int e = 0; e < cnt; ++e) {
      uint_t en = erow[e];
      int j = en & 511;
      if ((mb[row][j >> 6] >> (j & 63)) & 1ull) continue;
      float2 a = rg2[(en >> 9) & 1023];
      float2 c = rg2[en >> 19];
      float er = __expf(a.x + c.x);
      float gvv = a.y + c.y;
      float ev = b2f(S16[row][j]);
      S16[row][j] = f2b((1.f - gvv)*ev + gvv*er*sr);
    }
  }
  __syncthreads();

  // Phase 3: PV on e' (register-fed V), scaled by sinv[row] at the end
  {
    const ushort_t* prow = &S16[lrow][0];
    f32x4 o = (f32x4)(0.f);
    #pragma unroll
    for (int ks = 0; ks < 12; ++ks) {
      bf16x4 lo = *(const bf16x4*)(prow + ks*32 + lkg*8);
      bf16x4 hi = *(const bf16x4*)(prow + ks*32 + lkg*8 + 4);
      bf16x8 pa = __builtin_shufflevector(lo, hi, 0,1,2,3,4,5,6,7);
      o = __builtin_amdgcn_mfma_f32_16x16x32_bf16(pa, bv[ks], o, 0, 0, 0);
    }
    #pragma unroll
    for (int r = 0; r < 4; ++r) {
      float si = sinvS[4*lkg + r];
      ctxbf[((size_t)b*Lq + q0 + 4*lkg + r)*Dm + dcol] = f2b(o[r]*si);
    }
  }
}

extern "C" void kernel_launch(void* const* d_in, const int* in_sizes, int n_in,
                              void* d_out, int out_size, void* d_ws, size_t ws_size,
                              hipStream_t stream) {
  const float* queries   = (const float*)d_in[0];
  const float* keys      = (const float*)d_in[1];
  const float* values    = (const float*)d_in[2];
  const float* relations = (const float*)d_in[3];
  const int*   dp_map    = (const int*)d_in[4];
  const int*   mask      = (const int*)d_in[5];
  const int*   rel_mask  = (const int*)d_in[6];
  const float* Wq  = (const float*)d_in[7];
  const float* Wk  = (const float*)d_in[8];
  const float* Wv  = (const float*)d_in[9];
  const float* Wo  = (const float*)d_in[10];
  const float* Wge = (const float*)d_in[11];
  const float* Wgr = (const float*)d_in[12];
  const float* Vr  = (const float*)d_in[13];
  const float* Vg  = (const float*)d_in[14];

  float* ws = (float*)d_ws;
  const size_t SZ   = (size_t)Bn*Lq*Dm;      // 4718592
  const size_t WINS = (size_t)Bn*Lq*Lq;      // 2359296
  const size_t GSZ  = (size_t)Bn*Hn*Lq;      // 73728
  const size_t ROWS = (size_t)Bn*Lq;         // 6144

  int*   win  = (int*)ws;
  float* g    = ws + WINS;
  float* rlog = g + GSZ;
  float* Age  = rlog + GSZ;
  float* Agr  = Age + (size_t)Hn*Dm;
  ull_t* mbits = (ull_t*)(Agr + (size_t)Hn*Dm);
  int*   rowcnt = (int*)(mbits + ROWS*6);
  uint_t* ent  = (uint_t*)(rowcnt + ROWS);
  ushort_t* p0 = (ushort_t*)(ent + ROWS*ECAP);
  ushort_t* qbf  = p0;
  ushort_t* kbf  = p0 + SZ;
  ushort_t* vTbf = p0 + 2*SZ;
  ushort_t* ctxbf= p0 + 3*SZ;
  ushort_t* WqT  = p0 + 4*SZ;
  ushort_t* WkT  = WqT + (size_t)Dm*Dm;
  ushort_t* WvT  = WkT + (size_t)Dm*Dm;
  ushort_t* WoT  = WvT + (size_t)Dm*Dm;

  float* outp = (float*)d_out;               // (B,L,D)
  float* awp  = outp + SZ;                   // (B,L,L)

  hipMemsetAsync(win, 0xFF, WINS*sizeof(int), stream);
  hipMemsetAsync(rowcnt, 0, ROWS*sizeof(int), stream);
  k_prep<<<3888, 256, 0, stream>>>(Wge, Wgr, Vg, Age, Agr,
                                   Wq, Wk, Wv, Wo, WqT, WkT, WvT, WoT,
                                   dp_map, win, mask, mbits);
  k_grlog<<<Bn*Lq/4, 256, 0, stream>>>(values, relations, dp_map, rel_mask,
                                       Age, Agr, Vr, g, rlog);
  k_mmqkv<<<dim3(48, 6, 3), 256, 0, stream>>>(queries, keys, values,
                                              WqT, WkT, WvT, qbf, kbf, vTbf);
  k_collect<<<dim3(12, 12, Bn), 256, 0, stream>>>(win, ent, rowcnt);
  k_mm64<3><<<dim3(6, 3, Bn), 256, 0, stream>>>(qbf, kbf, awp, mask, 1.f/12.f);
  k_attn3<<<Bn*(Lq/QT2)*Hn, 256, 0, stream>>>(qbf, kbf, vTbf, mbits, rowcnt,
                                              ent, g, rlog, ctxbf);
  k_mm64<0><<<dim3(96, 6, 1), 256, 0, stream>>>(ctxbf, WoT, outp, nullptr, 1.f);
}

// Round 12
// 195.003 us; speedup vs baseline: 1.5525x; 1.5525x over previous
//
#include <hip/hip_runtime.h>
#include <math.h>

#define Bn 16
#define Lq 384
#define Hn 12
#define Dm 768
#define DH 64
#define QT2 16
#define NEGV (-1e18f)
#define SPADU 404   // e/P row stride in ushort
#define ECAP 32     // per-row pair-entry capacity (data max ~8)

typedef __attribute__((ext_vector_type(4))) float f32x4;
typedef __attribute__((ext_vector_type(8))) __bf16 bf16x8;
typedef __attribute__((ext_vector_type(4))) __bf16 bf16x4;
typedef unsigned short ushort_t;
typedef unsigned int uint_t;
typedef unsigned long long ull_t;

__device__ __forceinline__ ushort_t f2b(float f) {
  return __builtin_bit_cast(ushort_t, (__bf16)f);   // native RNE cvt
}
__device__ __forceinline__ float b2f(ushort_t u) {
  return __uint_as_float(((unsigned int)u) << 16);
}
__device__ __forceinline__ bf16x8 cvt8(float4 a, float4 b) {
  bf16x8 r;
  r[0] = (__bf16)a.x; r[1] = (__bf16)a.y; r[2] = (__bf16)a.z; r[3] = (__bf16)a.w;
  r[4] = (__bf16)b.x; r[5] = (__bf16)b.y; r[6] = (__bf16)b.z; r[7] = (__bf16)b.w;
  return r;
}

// ---------------- merged prologue:
// [0,24): Age/Agr | [24,2328): weight transposes | [2328,2352): win scatter
// [2352,3888): mask bitmask rows (4 rows/block, 1 per wave)
__global__ __launch_bounds__(256) void k_prep(
    const float* __restrict__ Wge, const float* __restrict__ Wgr,
    const float* __restrict__ Vg,
    float* __restrict__ Age, float* __restrict__ Agr,
    const float* __restrict__ W0, const float* __restrict__ W1,
    const float* __restrict__ W2, const float* __restrict__ W3,
    ushort_t* __restrict__ T0, ushort_t* __restrict__ T1,
    ushort_t* __restrict__ T2, ushort_t* __restrict__ T3,
    const int* __restrict__ dp, int* __restrict__ win,
    const int* __restrict__ mask, ull_t* __restrict__ mbits)
{
  __shared__ float vg[DH];
  __shared__ float t[32][33];
  int blk = blockIdx.x;
  if (blk < 24) {
    int which = blk / Hn;
    int h = blk % Hn;
    const float* Wsrc = which ? Wgr : Wge;
    float* dst = which ? Agr : Age;
    if (threadIdx.x < DH) vg[threadIdx.x] = Vg[h*DH + threadIdx.x];
    __syncthreads();
    for (int d = threadIdx.x; d < Dm; d += 256) {
      const float* wrow = Wsrc + (size_t)d*Dm + h*DH;
      float s = 0.f;
      #pragma unroll 8
      for (int j = 0; j < DH; ++j) s = fmaf(wrow[j], vg[j], s);
      dst[h*Dm + d] = s;
    }
  } else if (blk < 24 + 2304) {
    int b2 = blk - 24;
    int z = b2 / 576, rem = b2 % 576;
    const float* W = (z == 0) ? W0 : (z == 1) ? W1 : (z == 2) ? W2 : W3;
    ushort_t* WT = (z == 0) ? T0 : (z == 1) ? T1 : (z == 2) ? T2 : T3;
    int k0 = (rem / 24)*32, n0 = (rem % 24)*32;
    int tx = threadIdx.x & 31, ty = threadIdx.x >> 5;
    #pragma unroll
    for (int r = 0; r < 4; ++r)
      t[ty + r*8][tx] = W[(size_t)(k0 + ty + r*8)*Dm + n0 + tx];
    __syncthreads();
    #pragma unroll
    for (int r = 0; r < 4; ++r)
      WT[(size_t)(n0 + ty + r*8)*Dm + k0 + tx] = f2b(t[tx][ty + r*8]);
  } else if (blk < 2352) {
    int i = (blk - 2328)*256 + threadIdx.x;
    int b = i / Lq, l = i % Lq;
    int p0 = dp[(size_t)(b*2+0)*Lq + l];
    int p1 = dp[(size_t)(b*2+1)*Lq + l];
    atomicMax(&win[(size_t)b*Lq*Lq + (size_t)p0*Lq + p1], l);
  } else {
    int rr = blk - 2352;                 // 0..1535
    int lane = threadIdx.x & 63, wave = threadIdx.x >> 6;
    int gi = rr*4 + wave;                // global row 0..6143
    const int* mrow = mask + (size_t)gi*Lq;
    ull_t w0 = __ballot(mrow[lane]        != 0);
    ull_t w1 = __ballot(mrow[lane + 64]   != 0);
    ull_t w2 = __ballot(mrow[lane + 128]  != 0);
    ull_t w3 = __ballot(mrow[lane + 192]  != 0);
    ull_t w4 = __ballot(mrow[lane + 256]  != 0);
    ull_t w5 = __ballot(mrow[lane + 320]  != 0);
    if (lane == 0) {
      ull_t* out = mbits + (size_t)gi*6;
      out[0] = w0; out[1] = w1; out[2] = w2;
      out[3] = w3; out[4] = w4; out[5] = w5;
    }
  }
}

// ---------------- collect sparse pair entries per row (win + win^T nonzeros)
__global__ __launch_bounds__(256) void k_collect(
    const int* __restrict__ win, uint_t* __restrict__ ent,
    int* __restrict__ rowcnt)
{
  __shared__ int tB[32][33];
  int b = blockIdx.z;
  int i0 = blockIdx.x*32, j0 = blockIdx.y*32;
  const int* wb = win + (size_t)b*Lq*Lq;
  int tx = threadIdx.x & 31, ty = threadIdx.x >> 5;
  #pragma unroll
  for (int rr = 0; rr < 4; ++rr) {
    int r = ty + rr*8;
    tB[r][tx] = wb[(size_t)(j0+r)*Lq + i0 + tx];
  }
  __syncthreads();
  #pragma unroll
  for (int rr = 0; rr < 4; ++rr) {
    int ti = ty + rr*8;
    int i = i0 + ti, j = j0 + tx;
    int l1 = wb[(size_t)i*Lq + j];
    int l2 = tB[tx][ti];
    if (l1 >= 0 || l2 >= 0) {
      int slot = atomicAdd(&rowcnt[(size_t)b*Lq + i], 1);
      if (slot < ECAP)
        ent[((size_t)b*Lq + i)*ECAP + slot] =
            (uint_t)j | ((uint_t)(l1 + 1) << 9) | ((uint_t)(l2 + 1) << 19);
    }
  }
}

// ---------------- g (tanh gate) and rlog; 4 l-rows per block, wave per row
__global__ __launch_bounds__(256) void k_grlog(
    const float* __restrict__ values, const float* __restrict__ relations,
    const int* __restrict__ dp, const int* __restrict__ rel_mask,
    const float* __restrict__ Age, const float* __restrict__ Agr,
    const float* __restrict__ Vr,
    float* __restrict__ g, float* __restrict__ rlog)
{
  int blk = blockIdx.x;
  int b = blk / (Lq/4), l0 = (blk % (Lq/4))*4;
  int tid = threadIdx.x, lane = tid & 63, wave = tid >> 6;
  __shared__ float relrow[4][Dm], hvrow[4][Dm];
  #pragma unroll
  for (int rr = 0; rr < 4; ++rr) {
    int l = l0 + rr;
    int rm = rel_mask[(size_t)b*Lq + l];
    int idx = dp[(size_t)(b*2)*Lq + l];
    const float* vrow = values + ((size_t)b*Lq + idx)*Dm;
    const float* rrow = relations + ((size_t)b*Lq + l)*Dm;
    for (int d = tid; d < Dm; d += 256) {
      relrow[rr][d] = rm ? 0.f : rrow[d];
      hvrow[rr][d]  = (rm || l == 0) ? 0.f : vrow[d];
    }
  }
  __syncthreads();
  int l = l0 + wave;
  for (int h = 0; h < Hn; ++h) {
    float p = 0.f;
    #pragma unroll
    for (int k = 0; k < Dm/64; ++k) {
      int d = lane + 64*k;
      p = fmaf(hvrow[wave][d], Age[h*Dm + d],
          fmaf(relrow[wave][d], Agr[h*Dm + d], p));
    }
    #pragma unroll
    for (int o = 32; o > 0; o >>= 1) p += __shfl_xor(p, o);
    if (lane == 0) g[((size_t)b*Hn + h)*Lq + l] = tanhf(p);
  }
  if (lane < Hn) {
    float s = 0.f;
    #pragma unroll 8
    for (int j = 0; j < DH; ++j)
      s = fmaf(relrow[wave][lane*DH + j], Vr[lane*DH + j], s);
    rlog[((size_t)b*Hn + lane)*Lq + l] = s;
  }
}

// ---------------- fused QKV projection GEMM, 64x128 tile (high occupancy)
// blockIdx: (bm 0..95, bn 0..5, z: 0=q x0.125, 1=k, 2=v transposed)
__global__ __launch_bounds__(256) void k_mmqkv(
    const float* __restrict__ Xq, const float* __restrict__ Xk,
    const float* __restrict__ Xv,
    const ushort_t* __restrict__ WqT, const ushort_t* __restrict__ WkT,
    const ushort_t* __restrict__ WvT,
    ushort_t* __restrict__ qbf, ushort_t* __restrict__ kbf,
    ushort_t* __restrict__ vTbf)
{
  __shared__ ushort_t As[64*64];    // 8KB
  __shared__ ushort_t Bs[128*64];   // 16KB

  int z = blockIdx.z;
  const float* A     = (z == 0) ? Xq : (z == 1) ? Xk : Xv;
  const ushort_t* BT = (z == 0) ? WqT : (z == 1) ? WkT : WvT;

  int bm = blockIdx.x;              // 0..95 (64-row tiles)
  int bn = blockIdx.y;              // 0..5
  int m0 = bm*64, n0 = bn*128;

  int t = threadIdx.x;
  int wave = t >> 6, lane = t & 63;
  int wr = wave >> 1, wc = wave & 1;
  int lrow = lane & 15, lkg = lane >> 4;
  int sr = t >> 3, sc8 = t & 7;

  f32x4 acc[2][4];
  #pragma unroll
  for (int i = 0; i < 2; ++i)
    #pragma unroll
    for (int j = 0; j < 4; ++j) acc[i][j] = (f32x4)(0.f);

  for (int k0 = 0; k0 < Dm; k0 += 64) {
    __syncthreads();
    #pragma unroll
    for (int i = 0; i < 2; ++i) {
      int row = sr + i*32;
      const float* ap = A + (size_t)(m0 + row)*Dm + k0 + sc8*8;
      float4 f0 = *(const float4*)ap;
      float4 f1 = *(const float4*)(ap + 4);
      *(bf16x8*)&As[row*64 + (sc8 ^ (row & 7))*8] = cvt8(f0, f1);
    }
    #pragma unroll
    for (int i = 0; i < 4; ++i) {
      int row = sr + i*32;
      uint4 vb = *(const uint4*)(BT + (size_t)(n0 + row)*Dm + k0 + sc8*8);
      *(uint4*)&Bs[row*64 + (sc8 ^ (row & 7))*8] = vb;
    }
    __syncthreads();
    #pragma unroll
    for (int kk = 0; kk < 2; ++kk) {
      bf16x8 aF[2], bF[4];
      int chunk = kk*4 + lkg;
      #pragma unroll
      for (int mi = 0; mi < 2; ++mi) {
        int arow = wr*32 + mi*16 + lrow;
        aF[mi] = *(const bf16x8*)&As[arow*64 + ((chunk ^ (arow & 7)) << 3)];
      }
      #pragma unroll
      for (int ni = 0; ni < 4; ++ni) {
        int brow = wc*64 + ni*16 + lrow;
        bF[ni] = *(const bf16x8*)&Bs[brow*64 + ((chunk ^ (brow & 7)) << 3)];
      }
      #pragma unroll
      for (int mi = 0; mi < 2; ++mi)
        #pragma unroll
        for (int ni = 0; ni < 4; ++ni)
          acc[mi][ni] = __builtin_amdgcn_mfma_f32_16x16x32_bf16(
              aF[mi], bF[ni], acc[mi][ni], 0, 0, 0);
    }
  }

  float alpha = (z == 0) ? 0.125f : 1.f;
  #pragma unroll
  for (int mi = 0; mi < 2; ++mi) {
    #pragma unroll
    for (int ni = 0; ni < 4; ++ni) {
      f32x4 a = acc[mi][ni];
      int rit = wr*32 + mi*16 + 4*lkg;
      int cit = wc*64 + ni*16 + lrow;
      int gcol = n0 + cit;
      if (z < 2) {
        ushort_t* Cb = z ? kbf : qbf;
        int grow = m0 + rit;
        #pragma unroll
        for (int r = 0; r < 4; ++r)
          Cb[(size_t)(grow + r)*Dm + gcol] = f2b(a[r]*alpha);
      } else {
        int b = bm/6;
        int rl = (bm%6)*64 + rit;
        ushort4 u;
        u.x = f2b(a[0]); u.y = f2b(a[1]); u.z = f2b(a[2]); u.w = f2b(a[3]);
        *(ushort4*)&vTbf[((size_t)b*Dm + gcol)*Lq + rl] = u;
      }
    }
  }
}

// ---------------- 64x128-tile bf16 GEMM. MODE 0: C[M][768] f32 (grid 96,6,1).
// MODE 3: batched aw, per-batch M=N=384, mask epilogue (grid 6,3,16).
template<int MODE>
__global__ __launch_bounds__(256) void k_mm64(
    const ushort_t* __restrict__ A, const ushort_t* __restrict__ BT,
    float* __restrict__ Cf, const int* __restrict__ mask, float alpha)
{
  const int K = Dm;
  __shared__ ushort_t As[64*64];    // 8KB
  __shared__ ushort_t Bs[128*64];   // 16KB

  int bm = blockIdx.x, bn = blockIdx.y, b = blockIdx.z;
  const ushort_t* Ab = (MODE == 3) ? A  + (size_t)b*Lq*Dm : A;
  const ushort_t* Bb = (MODE == 3) ? BT + (size_t)b*Lq*Dm : BT;
  int m0 = bm*64, n0 = bn*128;

  int t = threadIdx.x;
  int wave = t >> 6, lane = t & 63;
  int wr = wave >> 1, wc = wave & 1;
  int lrow = lane & 15, lkg = lane >> 4;

  f32x4 acc[2][4];
  #pragma unroll
  for (int i = 0; i < 2; ++i)
    #pragma unroll
    for (int j = 0; j < 4; ++j) acc[i][j] = (f32x4)(0.f);

  int sr = t >> 3, sc8 = t & 7;
  for (int k0 = 0; k0 < K; k0 += 64) {
    __syncthreads();
    #pragma unroll
    for (int i = 0; i < 2; ++i) {
      int row = sr + i*32;
      uint4 va = *(const uint4*)(Ab + (size_t)(m0 + row)*K + k0 + sc8*8);
      int slot = sc8 ^ (row & 7);
      *(uint4*)&As[row*64 + slot*8] = va;
    }
    #pragma unroll
    for (int i = 0; i < 4; ++i) {
      int row = sr + i*32;
      uint4 vb = *(const uint4*)(Bb + (size_t)(n0 + row)*K + k0 + sc8*8);
      int slot = sc8 ^ (row & 7);
      *(uint4*)&Bs[row*64 + slot*8] = vb;
    }
    __syncthreads();
    #pragma unroll
    for (int kk = 0; kk < 2; ++kk) {
      bf16x8 aF[2], bF[4];
      int chunk = kk*4 + lkg;
      #pragma unroll
      for (int mi = 0; mi < 2; ++mi) {
        int arow = wr*32 + mi*16 + lrow;
        aF[mi] = *(const bf16x8*)&As[arow*64 + ((chunk ^ (arow & 7)) << 3)];
      }
      #pragma unroll
      for (int ni = 0; ni < 4; ++ni) {
        int brow = wc*64 + ni*16 + lrow;
        bF[ni] = *(const bf16x8*)&Bs[brow*64 + ((chunk ^ (brow & 7)) << 3)];
      }
      #pragma unroll
      for (int mi = 0; mi < 2; ++mi)
        #pragma unroll
        for (int ni = 0; ni < 4; ++ni)
          acc[mi][ni] = __builtin_amdgcn_mfma_f32_16x16x32_bf16(
              aF[mi], bF[ni], acc[mi][ni], 0, 0, 0);
    }
  }

  #pragma unroll
  for (int mi = 0; mi < 2; ++mi) {
    #pragma unroll
    for (int ni = 0; ni < 4; ++ni) {
      f32x4 a = acc[mi][ni];
      int rit = wr*32 + mi*16 + 4*lkg;
      int cit = wc*64 + ni*16 + lrow;
      if (MODE == 0) {
        int grow = m0 + rit, gcol = n0 + cit;
        #pragma unroll
        for (int r = 0; r < 4; ++r)
          Cf[(size_t)(grow + r)*Dm + gcol] = a[r]*alpha;
      } else {
        int rl = m0 + rit, cl = n0 + cit;
        const int* mb2 = mask + (size_t)b*Lq*Lq;
        float* awb = Cf + (size_t)b*Lq*Lq;
        #pragma unroll
        for (int r = 0; r < 4; ++r) {
          int m = mb2[(size_t)(rl + r)*Lq + cl];
          awb[(size_t)(rl + r)*Lq + cl] = m ? NEGV : a[r]*alpha;
        }
      }
    }
  }
}

// ---------------- fused per-(b,h,16-q-rows) attention, MFMA QK + PV
// e kept in regs through reduction; written to LDS once; P never materialized
// (pair entries patched in-place, PV scaled by 1/ssum at the end).
__global__ __launch_bounds__(256, 8) void k_attn3(
    const ushort_t* __restrict__ qbf, const ushort_t* __restrict__ kbf,
    const ushort_t* __restrict__ vT,
    const ull_t* __restrict__ mbits, const int* __restrict__ rowcnt,
    const uint_t* __restrict__ ent,
    const float* __restrict__ g, const float* __restrict__ rlog,
    ushort_t* __restrict__ ctxbf)
{
  __shared__ ushort_t S16[QT2][SPADU];  // 12.9KB: e (exp, masked), patched
  __shared__ ull_t mb[QT2][6];          // 768B: mask bitmask rows
  __shared__ float2 rg2[Lq + 1];        // 3.1KB: (rlog, g), zero slot at 0
  __shared__ uint_t entS[QT2*ECAP];     // 2KB
  __shared__ int cntS[QT2];             // 64B
  __shared__ float pp[QT2][4];          // 256B: per-wave partial ssums
  __shared__ float sinvS[QT2];          // 64B

  int bid = blockIdx.x;
  int h  = bid % Hn;
  int qt = (bid / Hn) % (Lq/QT2);
  int b  = bid / (Hn * (Lq/QT2));
  int q0 = qt * QT2;
  int tid = threadIdx.x, lane = tid & 63, wave = tid >> 6;
  int lrow = lane & 15, lkg = lane >> 4;

  const float* gh = g    + ((size_t)b*Hn + h)*Lq;
  const float* rh = rlog + ((size_t)b*Hn + h)*Lq;

  // ---- prefetch all phase-2 inputs ----
  if (tid < QT2*6) {
    int r = tid / 6, u = tid % 6;
    mb[r][u] = mbits[((size_t)b*Lq + q0 + r)*6 + u];
  }
  if (tid == 0) { rg2[0].x = 0.f; rg2[0].y = 0.f; }
  for (int e = tid; e < Lq; e += 256) {
    float2 v2; v2.x = rh[e]; v2.y = gh[e];
    rg2[e + 1] = v2;
  }
  #pragma unroll
  for (int e = tid; e < QT2*ECAP; e += 256)
    entS[e] = ent[((size_t)b*Lq + q0)*ECAP + e];
  if (tid < QT2) {
    int c = rowcnt[(size_t)b*Lq + q0 + tid];
    cntS[tid] = c > ECAP ? ECAP : c;
  }
  __syncthreads();   // mb visible to phase 1

  // Phase 1: QK MFMA -> mask-zero -> exp -> reg partial sums + single e write
  {
    const ushort_t* qb = qbf + ((size_t)b*Lq + q0 + lrow)*Dm + h*DH + lkg*8;
    bf16x8 aF0 = *(const bf16x8*)(qb);
    bf16x8 aF1 = *(const bf16x8*)(qb + 32);
    int col0 = wave*96;
    int w0 = col0 >> 6;
    ull_t m0[4], m1[4];
    #pragma unroll
    for (int r = 0; r < 4; ++r) {
      m0[r] = mb[4*lkg + r][w0];
      m1[r] = mb[4*lkg + r][w0 + 1];
    }
    float ps[4] = {0.f, 0.f, 0.f, 0.f};
    const ushort_t* kb = kbf + ((size_t)b*Lq + col0 + lrow)*Dm + h*DH + lkg*8;
    #pragma unroll
    for (int tt = 0; tt < 6; ++tt) {
      int col = col0 + tt*16 + lrow;
      bf16x8 bF0 = *(const bf16x8*)(kb);
      bf16x8 bF1 = *(const bf16x8*)(kb + 32);
      kb += 16*Dm;
      f32x4 z = (f32x4)(0.f);
      z = __builtin_amdgcn_mfma_f32_16x16x32_bf16(aF0, bF0, z, 0, 0, 0);
      z = __builtin_amdgcn_mfma_f32_16x16x32_bf16(aF1, bF1, z, 0, 0, 0);
      bool hi = ((col0 + tt*16) >> 6) != w0;
      int sh = col & 63;
      #pragma unroll
      for (int r = 0; r < 4; ++r) {
        ull_t mw = hi ? m1[r] : m0[r];
        bool mk = (mw >> sh) & 1ull;
        float e = mk ? 0.f : __expf(z[r]);
        ps[r] += e;
        S16[4*lkg + r][col] = f2b(e);
      }
    }
    #pragma unroll
    for (int off = 1; off < 16; off <<= 1)
      #pragma unroll
      for (int r = 0; r < 4; ++r) ps[r] += __shfl_xor(ps[r], off);
    if (lrow == 0) {
      #pragma unroll
      for (int r = 0; r < 4; ++r) pp[4*lkg + r][wave] = ps[r];
    }
  }
  __syncthreads();

  // Phase 2: 16 threads — sinv per row + in-place pair patches on e
  if (tid < QT2) {
    int row = tid;
    float ssum = pp[row][0] + pp[row][1] + pp[row][2] + pp[row][3];
    float si = 1.f / ssum;
    sinvS[row] = si;
    int nun = 384;
    #pragma unroll
    for (int u = 0; u < 6; ++u) nun -= (int)__popcll(mb[row][u]);
    int cnt = cntS[row];
    const uint_t* erow = &entS[row*ECAP];
    float rext = 0.f;
    for (int e = 0; e < cnt; ++e) {
      uint_t en = erow[e];
      int j = en & 511;
      if ((mb[row][j >> 6] >> (j & 63)) & 1ull) continue;
      float rel = rg2[(en >> 9) & 1023].x + rg2[en >> 19].x;
      rext += __expf(rel) - 1.f;
    }
    float sr = ssum / ((float)nun + rext);   // ssum * rinv
    for (int e = 0; e < cnt; ++e) {
      uint_t en = erow[e];
      int j = en & 511;
      if ((mb[row][j >> 6] >> (j & 63)) & 1ull) continue;
      float2 a = rg2[(en >> 9) & 1023];
      float2 c = rg2[en >> 19];
      float er = __expf(a.x + c.x);
      float gvv = a.y + c.y;
      float ev = b2f(S16[row][j]);
      S16[row][j] = f2b((1.f - gvv)*ev + gvv*er*sr);
    }
  }
  __syncthreads();

  // Phase 3: PV on e', scaled by sinv[row] at the end
  {
    int dcol = h*DH + wave*16 + lrow;
    const ushort_t* vb = vT + ((size_t)b*Dm + dcol)*Lq + lkg*8;
    const ushort_t* prow = &S16[lrow][0];
    f32x4 o = (f32x4)(0.f);
    #pragma unroll
    for (int ks = 0; ks < 12; ++ks) {
      bf16x4 lo = *(const bf16x4*)(prow + ks*32 + lkg*8);
      bf16x4 hi = *(const bf16x4*)(prow + ks*32 + lkg*8 + 4);
      bf16x8 pa = __builtin_shufflevector(lo, hi, 0,1,2,3,4,5,6,7);
      bf16x8 bv = *(const bf16x8*)(vb + ks*32);
      o = __builtin_amdgcn_mfma_f32_16x16x32_bf16(pa, bv, o, 0, 0, 0);
    }
    #pragma unroll
    for (int r = 0; r < 4; ++r) {
      float si = sinvS[4*lkg + r];
      ctxbf[((size_t)b*Lq + q0 + 4*lkg + r)*Dm + dcol] = f2b(o[r]*si);
    }
  }
}

extern "C" void kernel_launch(void* const* d_in, const int* in_sizes, int n_in,
                              void* d_out, int out_size, void* d_ws, size_t ws_size,
                              hipStream_t stream) {
  const float* queries   = (const float*)d_in[0];
  const float* keys      = (const float*)d_in[1];
  const float* values    = (const float*)d_in[2];
  const float* relations = (const float*)d_in[3];
  const int*   dp_map    = (const int*)d_in[4];
  const int*   mask      = (const int*)d_in[5];
  const int*   rel_mask  = (const int*)d_in[6];
  const float* Wq  = (const float*)d_in[7];
  const float* Wk  = (const float*)d_in[8];
  const float* Wv  = (const float*)d_in[9];
  const float* Wo  = (const float*)d_in[10];
  const float* Wge = (const float*)d_in[11];
  const float* Wgr = (const float*)d_in[12];
  const float* Vr  = (const float*)d_in[13];
  const float* Vg  = (const float*)d_in[14];

  float* ws = (float*)d_ws;
  const size_t SZ   = (size_t)Bn*Lq*Dm;      // 4718592
  const size_t WINS = (size_t)Bn*Lq*Lq;      // 2359296
  const size_t GSZ  = (size_t)Bn*Hn*Lq;      // 73728
  const size_t ROWS = (size_t)Bn*Lq;         // 6144

  int*   win  = (int*)ws;
  float* g    = ws + WINS;
  float* rlog = g + GSZ;
  float* Age  = rlog + GSZ;
  float* Agr  = Age + (size_t)Hn*Dm;
  ull_t* mbits = (ull_t*)(Agr + (size_t)Hn*Dm);
  int*   rowcnt = (int*)(mbits + ROWS*6);
  uint_t* ent  = (uint_t*)(rowcnt + ROWS);
  ushort_t* p0 = (ushort_t*)(ent + ROWS*ECAP);
  ushort_t* qbf  = p0;
  ushort_t* kbf  = p0 + SZ;
  ushort_t* vTbf = p0 + 2*SZ;
  ushort_t* ctxbf= p0 + 3*SZ;
  ushort_t* WqT  = p0 + 4*SZ;
  ushort_t* WkT  = WqT + (size_t)Dm*Dm;
  ushort_t* WvT  = WkT + (size_t)Dm*Dm;
  ushort_t* WoT  = WvT + (size_t)Dm*Dm;

  float* outp = (float*)d_out;               // (B,L,D)
  float* awp  = outp + SZ;                   // (B,L,L)

  hipMemsetAsync(win, 0xFF, WINS*sizeof(int), stream);
  hipMemsetAsync(rowcnt, 0, ROWS*sizeof(int), stream);
  k_prep<<<3888, 256, 0, stream>>>(Wge, Wgr, Vg, Age, Agr,
                                   Wq, Wk, Wv, Wo, WqT, WkT, WvT, WoT,
                                   dp_map, win, mask, mbits);
  k_grlog<<<Bn*Lq/4, 256, 0, stream>>>(values, relations, dp_map, rel_mask,
                                       Age, Agr, Vr, g, rlog);
  k_mmqkv<<<dim3(96, 6, 3), 256, 0, stream>>>(queries, keys, values,
                                              WqT, WkT, WvT, qbf, kbf, vTbf);
  k_collect<<<dim3(12, 12, Bn), 256, 0, stream>>>(win, ent, rowcnt);
  k_mm64<3><<<dim3(6, 3, Bn), 256, 0, stream>>>(qbf, kbf, awp, mask, 1.f/12.f);
  k_attn3<<<Bn*(Lq/QT2)*Hn, 256, 0, stream>>>(qbf, kbf, vTbf, mbits, rowcnt,
                                              ent, g, rlog, ctxbf);
  k_mm64<0><<<dim3(96, 6, 1), 256, 0, stream>>>(ctxbf, WoT, outp, nullptr, 1.f);
}

// Round 13
// 180.609 us; speedup vs baseline: 1.6762x; 1.0797x over previous
//
#include <hip/hip_runtime.h>
#include <math.h>

#define Bn 16
#define Lq 384
#define Hn 12
#define Dm 768
#define DH 64
#define QT2 16
#define NEGV (-1e18f)
#define SPADU 404   // e/P row stride in ushort
#define ECAP 32     // per-row pair-entry capacity (data max ~8)

typedef __attribute__((ext_vector_type(4))) float f32x4;
typedef __attribute__((ext_vector_type(8))) __bf16 bf16x8;
typedef __attribute__((ext_vector_type(4))) __bf16 bf16x4;
typedef unsigned short ushort_t;
typedef unsigned int uint_t;
typedef unsigned long long ull_t;

__device__ __forceinline__ ushort_t f2b(float f) {
  return __builtin_bit_cast(ushort_t, (__bf16)f);   // native RNE cvt
}
__device__ __forceinline__ float b2f(ushort_t u) {
  return __uint_as_float(((unsigned int)u) << 16);
}
__device__ __forceinline__ bf16x8 cvt8(float4 a, float4 b) {
  bf16x8 r;
  r[0] = (__bf16)a.x; r[1] = (__bf16)a.y; r[2] = (__bf16)a.z; r[3] = (__bf16)a.w;
  r[4] = (__bf16)b.x; r[5] = (__bf16)b.y; r[6] = (__bf16)b.z; r[7] = (__bf16)b.w;
  return r;
}

#define SMEM_BYTES 24576

// ---------------- merged prologue (unchanged from R12):
// [0,24): Age/Agr | [24,2328): weight transposes | [2328,2352): win scatter
// [2352,3888): mask bitmask rows
__global__ __launch_bounds__(256) void k_prep(
    const float* __restrict__ Wge, const float* __restrict__ Wgr,
    const float* __restrict__ Vg,
    float* __restrict__ Age, float* __restrict__ Agr,
    const float* __restrict__ W0, const float* __restrict__ W1,
    const float* __restrict__ W2, const float* __restrict__ W3,
    ushort_t* __restrict__ T0, ushort_t* __restrict__ T1,
    ushort_t* __restrict__ T2, ushort_t* __restrict__ T3,
    const int* __restrict__ dp, int* __restrict__ win,
    const int* __restrict__ mask, ull_t* __restrict__ mbits)
{
  __shared__ float vg[DH];
  __shared__ float t[32][33];
  int blk = blockIdx.x;
  if (blk < 24) {
    int which = blk / Hn;
    int h = blk % Hn;
    const float* Wsrc = which ? Wgr : Wge;
    float* dst = which ? Agr : Age;
    if (threadIdx.x < DH) vg[threadIdx.x] = Vg[h*DH + threadIdx.x];
    __syncthreads();
    for (int d = threadIdx.x; d < Dm; d += 256) {
      const float* wrow = Wsrc + (size_t)d*Dm + h*DH;
      float s = 0.f;
      #pragma unroll 8
      for (int j = 0; j < DH; ++j) s = fmaf(wrow[j], vg[j], s);
      dst[h*Dm + d] = s;
    }
  } else if (blk < 24 + 2304) {
    int b2 = blk - 24;
    int z = b2 / 576, rem = b2 % 576;
    const float* W = (z == 0) ? W0 : (z == 1) ? W1 : (z == 2) ? W2 : W3;
    ushort_t* WT = (z == 0) ? T0 : (z == 1) ? T1 : (z == 2) ? T2 : T3;
    int k0 = (rem / 24)*32, n0 = (rem % 24)*32;
    int tx = threadIdx.x & 31, ty = threadIdx.x >> 5;
    #pragma unroll
    for (int r = 0; r < 4; ++r)
      t[ty + r*8][tx] = W[(size_t)(k0 + ty + r*8)*Dm + n0 + tx];
    __syncthreads();
    #pragma unroll
    for (int r = 0; r < 4; ++r)
      WT[(size_t)(n0 + ty + r*8)*Dm + k0 + tx] = f2b(t[tx][ty + r*8]);
  } else if (blk < 2352) {
    int i = (blk - 2328)*256 + threadIdx.x;
    int b = i / Lq, l = i % Lq;
    int p0 = dp[(size_t)(b*2+0)*Lq + l];
    int p1 = dp[(size_t)(b*2+1)*Lq + l];
    atomicMax(&win[(size_t)b*Lq*Lq + (size_t)p0*Lq + p1], l);
  } else {
    int rr = blk - 2352;
    int lane = threadIdx.x & 63, wave = threadIdx.x >> 6;
    int gi = rr*4 + wave;
    const int* mrow = mask + (size_t)gi*Lq;
    ull_t w0 = __ballot(mrow[lane]        != 0);
    ull_t w1 = __ballot(mrow[lane + 64]   != 0);
    ull_t w2 = __ballot(mrow[lane + 128]  != 0);
    ull_t w3 = __ballot(mrow[lane + 192]  != 0);
    ull_t w4 = __ballot(mrow[lane + 256]  != 0);
    ull_t w5 = __ballot(mrow[lane + 320]  != 0);
    if (lane == 0) {
      ull_t* out = mbits + (size_t)gi*6;
      out[0] = w0; out[1] = w1; out[2] = w2;
      out[3] = w3; out[4] = w4; out[5] = w5;
    }
  }
}

// ================ device bodies for fused launches ================

__device__ void dev_grlog(char* sm, int blk,
    const float* __restrict__ values, const float* __restrict__ relations,
    const int* __restrict__ dp, const int* __restrict__ rel_mask,
    const float* __restrict__ Age, const float* __restrict__ Agr,
    const float* __restrict__ Vr, float* __restrict__ g, float* __restrict__ rlog)
{
  float (*relrow)[Dm] = (float(*)[Dm])sm;
  float (*hvrow)[Dm]  = (float(*)[Dm])(sm + 4*Dm*sizeof(float));
  int b = blk / (Lq/4), l0 = (blk % (Lq/4))*4;
  int tid = threadIdx.x, lane = tid & 63, wave = tid >> 6;
  #pragma unroll
  for (int rr = 0; rr < 4; ++rr) {
    int l = l0 + rr;
    int rm = rel_mask[(size_t)b*Lq + l];
    int idx = dp[(size_t)(b*2)*Lq + l];
    const float* vrow = values + ((size_t)b*Lq + idx)*Dm;
    const float* rrow = relations + ((size_t)b*Lq + l)*Dm;
    for (int d = tid; d < Dm; d += 256) {
      relrow[rr][d] = rm ? 0.f : rrow[d];
      hvrow[rr][d]  = (rm || l == 0) ? 0.f : vrow[d];
    }
  }
  __syncthreads();
  int l = l0 + wave;
  for (int h = 0; h < Hn; ++h) {
    float p = 0.f;
    #pragma unroll
    for (int k = 0; k < Dm/64; ++k) {
      int d = lane + 64*k;
      p = fmaf(hvrow[wave][d], Age[h*Dm + d],
          fmaf(relrow[wave][d], Agr[h*Dm + d], p));
    }
    #pragma unroll
    for (int o = 32; o > 0; o >>= 1) p += __shfl_xor(p, o);
    if (lane == 0) g[((size_t)b*Hn + h)*Lq + l] = tanhf(p);
  }
  if (lane < Hn) {
    float s = 0.f;
    #pragma unroll 8
    for (int j = 0; j < DH; ++j)
      s = fmaf(relrow[wave][lane*DH + j], Vr[lane*DH + j], s);
    rlog[((size_t)b*Hn + lane)*Lq + l] = s;
  }
}

__device__ void dev_mmqkv(char* sm, int bm, int bn, int z,
    const float* __restrict__ Xq, const float* __restrict__ Xk,
    const float* __restrict__ Xv,
    const ushort_t* __restrict__ WqT, const ushort_t* __restrict__ WkT,
    const ushort_t* __restrict__ WvT,
    ushort_t* __restrict__ qbf, ushort_t* __restrict__ kbf,
    ushort_t* __restrict__ vTbf)
{
  ushort_t* As = (ushort_t*)sm;              // 64*64
  ushort_t* Bs = (ushort_t*)(sm + 8192);     // 128*64
  const float* A     = (z == 0) ? Xq : (z == 1) ? Xk : Xv;
  const ushort_t* BT = (z == 0) ? WqT : (z == 1) ? WkT : WvT;
  int m0 = bm*64, n0 = bn*128;
  int t = threadIdx.x;
  int wave = t >> 6, lane = t & 63;
  int wr = wave >> 1, wc = wave & 1;
  int lrow = lane & 15, lkg = lane >> 4;
  int sr = t >> 3, sc8 = t & 7;

  f32x4 acc[2][4];
  #pragma unroll
  for (int i = 0; i < 2; ++i)
    #pragma unroll
    for (int j = 0; j < 4; ++j) acc[i][j] = (f32x4)(0.f);

  for (int k0 = 0; k0 < Dm; k0 += 64) {
    __syncthreads();
    #pragma unroll
    for (int i = 0; i < 2; ++i) {
      int row = sr + i*32;
      const float* ap = A + (size_t)(m0 + row)*Dm + k0 + sc8*8;
      float4 f0 = *(const float4*)ap;
      float4 f1 = *(const float4*)(ap + 4);
      *(bf16x8*)&As[row*64 + (sc8 ^ (row & 7))*8] = cvt8(f0, f1);
    }
    #pragma unroll
    for (int i = 0; i < 4; ++i) {
      int row = sr + i*32;
      uint4 vb = *(const uint4*)(BT + (size_t)(n0 + row)*Dm + k0 + sc8*8);
      *(uint4*)&Bs[row*64 + (sc8 ^ (row & 7))*8] = vb;
    }
    __syncthreads();
    #pragma unroll
    for (int kk = 0; kk < 2; ++kk) {
      bf16x8 aF[2], bF[4];
      int chunk = kk*4 + lkg;
      #pragma unroll
      for (int mi = 0; mi < 2; ++mi) {
        int arow = wr*32 + mi*16 + lrow;
        aF[mi] = *(const bf16x8*)&As[arow*64 + ((chunk ^ (arow & 7)) << 3)];
      }
      #pragma unroll
      for (int ni = 0; ni < 4; ++ni) {
        int brow = wc*64 + ni*16 + lrow;
        bF[ni] = *(const bf16x8*)&Bs[brow*64 + ((chunk ^ (brow & 7)) << 3)];
      }
      #pragma unroll
      for (int mi = 0; mi < 2; ++mi)
        #pragma unroll
        for (int ni = 0; ni < 4; ++ni)
          acc[mi][ni] = __builtin_amdgcn_mfma_f32_16x16x32_bf16(
              aF[mi], bF[ni], acc[mi][ni], 0, 0, 0);
    }
  }

  float alpha = (z == 0) ? 0.125f : 1.f;
  #pragma unroll
  for (int mi = 0; mi < 2; ++mi) {
    #pragma unroll
    for (int ni = 0; ni < 4; ++ni) {
      f32x4 a = acc[mi][ni];
      int rit = wr*32 + mi*16 + 4*lkg;
      int cit = wc*64 + ni*16 + lrow;
      int gcol = bn*128 + cit;
      if (z < 2) {
        ushort_t* Cb = z ? kbf : qbf;
        int grow = m0 + rit;
        #pragma unroll
        for (int r = 0; r < 4; ++r)
          Cb[(size_t)(grow + r)*Dm + gcol] = f2b(a[r]*alpha);
      } else {
        int b = bm/6;
        int rl = (bm%6)*64 + rit;
        ushort4 u;
        u.x = f2b(a[0]); u.y = f2b(a[1]); u.z = f2b(a[2]); u.w = f2b(a[3]);
        *(ushort4*)&vTbf[((size_t)b*Dm + gcol)*Lq + rl] = u;
      }
    }
  }
}

__device__ void dev_collect(char* sm, int i0b, int j0b, int b,
    const int* __restrict__ win, uint_t* __restrict__ ent,
    int* __restrict__ rowcnt)
{
  int (*tB)[33] = (int(*)[33])sm;
  int i0 = i0b*32, j0 = j0b*32;
  const int* wb = win + (size_t)b*Lq*Lq;
  int tx = threadIdx.x & 31, ty = threadIdx.x >> 5;
  #pragma unroll
  for (int rr = 0; rr < 4; ++rr) {
    int r = ty + rr*8;
    tB[r][tx] = wb[(size_t)(j0+r)*Lq + i0 + tx];
  }
  __syncthreads();
  #pragma unroll
  for (int rr = 0; rr < 4; ++rr) {
    int ti = ty + rr*8;
    int i = i0 + ti, j = j0 + tx;
    int l1 = wb[(size_t)i*Lq + j];
    int l2 = tB[tx][ti];
    if (l1 >= 0 || l2 >= 0) {
      int slot = atomicAdd(&rowcnt[(size_t)b*Lq + i], 1);
      if (slot < ECAP)
        ent[((size_t)b*Lq + i)*ECAP + slot] =
            (uint_t)j | ((uint_t)(l1 + 1) << 9) | ((uint_t)(l2 + 1) << 19);
    }
  }
}

// aw GEMM body (was k_mm64<3>)
__device__ void dev_aw(char* sm, int bm, int bn, int b,
    const ushort_t* __restrict__ A, const ushort_t* __restrict__ BT,
    float* __restrict__ Cf, const int* __restrict__ mask, float alpha)
{
  ushort_t* As = (ushort_t*)sm;
  ushort_t* Bs = (ushort_t*)(sm + 8192);
  const ushort_t* Ab = A  + (size_t)b*Lq*Dm;
  const ushort_t* Bb = BT + (size_t)b*Lq*Dm;
  int m0 = bm*64, n0 = bn*128;
  int t = threadIdx.x;
  int wave = t >> 6, lane = t & 63;
  int wr = wave >> 1, wc = wave & 1;
  int lrow = lane & 15, lkg = lane >> 4;
  int sr = t >> 3, sc8 = t & 7;

  f32x4 acc[2][4];
  #pragma unroll
  for (int i = 0; i < 2; ++i)
    #pragma unroll
    for (int j = 0; j < 4; ++j) acc[i][j] = (f32x4)(0.f);

  for (int k0 = 0; k0 < Dm; k0 += 64) {
    __syncthreads();
    #pragma unroll
    for (int i = 0; i < 2; ++i) {
      int row = sr + i*32;
      uint4 va = *(const uint4*)(Ab + (size_t)(m0 + row)*Dm + k0 + sc8*8);
      *(uint4*)&As[row*64 + (sc8 ^ (row & 7))*8] = va;
    }
    #pragma unroll
    for (int i = 0; i < 4; ++i) {
      int row = sr + i*32;
      uint4 vb = *(const uint4*)(Bb + (size_t)(n0 + row)*Dm + k0 + sc8*8);
      *(uint4*)&Bs[row*64 + (sc8 ^ (row & 7))*8] = vb;
    }
    __syncthreads();
    #pragma unroll
    for (int kk = 0; kk < 2; ++kk) {
      bf16x8 aF[2], bF[4];
      int chunk = kk*4 + lkg;
      #pragma unroll
      for (int mi = 0; mi < 2; ++mi) {
        int arow = wr*32 + mi*16 + lrow;
        aF[mi] = *(const bf16x8*)&As[arow*64 + ((chunk ^ (arow & 7)) << 3)];
      }
      #pragma unroll
      for (int ni = 0; ni < 4; ++ni) {
        int brow = wc*64 + ni*16 + lrow;
        bF[ni] = *(const bf16x8*)&Bs[brow*64 + ((chunk ^ (brow & 7)) << 3)];
      }
      #pragma unroll
      for (int mi = 0; mi < 2; ++mi)
        #pragma unroll
        for (int ni = 0; ni < 4; ++ni)
          acc[mi][ni] = __builtin_amdgcn_mfma_f32_16x16x32_bf16(
              aF[mi], bF[ni], acc[mi][ni], 0, 0, 0);
    }
  }

  #pragma unroll
  for (int mi = 0; mi < 2; ++mi) {
    #pragma unroll
    for (int ni = 0; ni < 4; ++ni) {
      f32x4 a = acc[mi][ni];
      int rit = wr*32 + mi*16 + 4*lkg;
      int cit = wc*64 + ni*16 + lrow;
      int rl = m0 + rit, cl = n0 + cit;
      const int* mb2 = mask + (size_t)b*Lq*Lq;
      float* awb = Cf + (size_t)b*Lq*Lq;
      #pragma unroll
      for (int r = 0; r < 4; ++r) {
        int m = mb2[(size_t)(rl + r)*Lq + cl];
        awb[(size_t)(rl + r)*Lq + cl] = m ? NEGV : a[r]*alpha;
      }
    }
  }
}

// attn3 body (unchanged R12 logic), smem overlay
struct AttnS {
  ushort_t S16[QT2][SPADU];   // 12928
  ull_t mb[QT2][6];           // 768
  float2 rg2[Lq + 1];         // 3080
  uint_t entS[QT2*ECAP];      // 2048
  int cntS[QT2];              // 64
  float pp[QT2][4];           // 256
  float sinvS[QT2];           // 64
};

__device__ void dev_attn3(char* sm, int bid,
    const ushort_t* __restrict__ qbf, const ushort_t* __restrict__ kbf,
    const ushort_t* __restrict__ vT,
    const ull_t* __restrict__ mbits, const int* __restrict__ rowcnt,
    const uint_t* __restrict__ ent,
    const float* __restrict__ g, const float* __restrict__ rlog,
    ushort_t* __restrict__ ctxbf)
{
  AttnS* S = (AttnS*)sm;
  int h  = bid % Hn;
  int qt = (bid / Hn) % (Lq/QT2);
  int b  = bid / (Hn * (Lq/QT2));
  int q0 = qt * QT2;
  int tid = threadIdx.x, lane = tid & 63, wave = tid >> 6;
  int lrow = lane & 15, lkg = lane >> 4;

  const float* gh = g    + ((size_t)b*Hn + h)*Lq;
  const float* rh = rlog + ((size_t)b*Hn + h)*Lq;

  if (tid < QT2*6) {
    int r = tid / 6, u = tid % 6;
    S->mb[r][u] = mbits[((size_t)b*Lq + q0 + r)*6 + u];
  }
  if (tid == 0) { S->rg2[0].x = 0.f; S->rg2[0].y = 0.f; }
  for (int e = tid; e < Lq; e += 256) {
    float2 v2; v2.x = rh[e]; v2.y = gh[e];
    S->rg2[e + 1] = v2;
  }
  #pragma unroll
  for (int e = tid; e < QT2*ECAP; e += 256)
    S->entS[e] = ent[((size_t)b*Lq + q0)*ECAP + e];
  if (tid < QT2) {
    int c = rowcnt[(size_t)b*Lq + q0 + tid];
    S->cntS[tid] = c > ECAP ? ECAP : c;
  }
  __syncthreads();

  // Phase 1
  {
    const ushort_t* qb = qbf + ((size_t)b*Lq + q0 + lrow)*Dm + h*DH + lkg*8;
    bf16x8 aF0 = *(const bf16x8*)(qb);
    bf16x8 aF1 = *(const bf16x8*)(qb + 32);
    int col0 = wave*96;
    int w0 = col0 >> 6;
    ull_t m0[4], m1[4];
    #pragma unroll
    for (int r = 0; r < 4; ++r) {
      m0[r] = S->mb[4*lkg + r][w0];
      m1[r] = S->mb[4*lkg + r][w0 + 1];
    }
    float ps[4] = {0.f, 0.f, 0.f, 0.f};
    const ushort_t* kb = kbf + ((size_t)b*Lq + col0 + lrow)*Dm + h*DH + lkg*8;
    #pragma unroll
    for (int tt = 0; tt < 6; ++tt) {
      int col = col0 + tt*16 + lrow;
      bf16x8 bF0 = *(const bf16x8*)(kb);
      bf16x8 bF1 = *(const bf16x8*)(kb + 32);
      kb += 16*Dm;
      f32x4 z = (f32x4)(0.f);
      z = __builtin_amdgcn_mfma_f32_16x16x32_bf16(aF0, bF0, z, 0, 0, 0);
      z = __builtin_amdgcn_mfma_f32_16x16x32_bf16(aF1, bF1, z, 0, 0, 0);
      bool hi = ((col0 + tt*16) >> 6) != w0;
      int sh = col & 63;
      #pragma unroll
      for (int r = 0; r < 4; ++r) {
        ull_t mw = hi ? m1[r] : m0[r];
        bool mk = (mw >> sh) & 1ull;
        float e = mk ? 0.f : __expf(z[r]);
        ps[r] += e;
        S->S16[4*lkg + r][col] = f2b(e);
      }
    }
    #pragma unroll
    for (int off = 1; off < 16; off <<= 1)
      #pragma unroll
      for (int r = 0; r < 4; ++r) ps[r] += __shfl_xor(ps[r], off);
    if (lrow == 0) {
      #pragma unroll
      for (int r = 0; r < 4; ++r) S->pp[4*lkg + r][wave] = ps[r];
    }
  }
  __syncthreads();

  // Phase 2
  if (tid < QT2) {
    int row = tid;
    float ssum = S->pp[row][0] + S->pp[row][1] + S->pp[row][2] + S->pp[row][3];
    float si = 1.f / ssum;
    S->sinvS[row] = si;
    int nun = 384;
    #pragma unroll
    for (int u = 0; u < 6; ++u) nun -= (int)__popcll(S->mb[row][u]);
    int cnt = S->cntS[row];
    const uint_t* erow = &S->entS[row*ECAP];
    float rext = 0.f;
    for (int e = 0; e < cnt; ++e) {
      uint_t en = erow[e];
      int j = en & 511;
      if ((S->mb[row][j >> 6] >> (j & 63)) & 1ull) continue;
      float rel = S->rg2[(en >> 9) & 1023].x + S->rg2[en >> 19].x;
      rext += __expf(rel) - 1.f;
    }
    float sr = ssum / ((float)nun + rext);
    for (int e = 0; e < cnt; ++e) {
      uint_t en = erow[e];
      int j = en & 511;
      if ((S->mb[row][j >> 6] >> (j & 63)) & 1ull) continue;
      float2 a = S->rg2[(en >> 9) & 1023];
      float2 c = S->rg2[en >> 19];
      float er = __expf(a.x + c.x);
      float gvv = a.y + c.y;
      float ev = b2f(S->S16[row][j]);
      S->S16[row][j] = f2b((1.f - gvv)*ev + gvv*er*sr);
    }
  }
  __syncthreads();

  // Phase 3
  {
    int dcol = h*DH + wave*16 + lrow;
    const ushort_t* vb = vT + ((size_t)b*Dm + dcol)*Lq + lkg*8;
    const ushort_t* prow = &S->S16[lrow][0];
    f32x4 o = (f32x4)(0.f);
    #pragma unroll
    for (int ks = 0; ks < 12; ++ks) {
      bf16x4 lo = *(const bf16x4*)(prow + ks*32 + lkg*8);
      bf16x4 hi = *(const bf16x4*)(prow + ks*32 + lkg*8 + 4);
      bf16x8 pa = __builtin_shufflevector(lo, hi, 0,1,2,3,4,5,6,7);
      bf16x8 bv = *(const bf16x8*)(vb + ks*32);
      o = __builtin_amdgcn_mfma_f32_16x16x32_bf16(pa, bv, o, 0, 0, 0);
    }
    #pragma unroll
    for (int r = 0; r < 4; ++r) {
      float si = S->sinvS[4*lkg + r];
      ctxbf[((size_t)b*Lq + q0 + 4*lkg + r)*Dm + dcol] = f2b(o[r]*si);
    }
  }
}

// ================ fused launches ================

// mega1: [0,1536) grlog | [1536,3264) mmqkv | [3264,5568) collect
__global__ __launch_bounds__(256) void k_mega1(
    const float* __restrict__ values, const float* __restrict__ relations,
    const int* __restrict__ dp, const int* __restrict__ rel_mask,
    const float* __restrict__ Age, const float* __restrict__ Agr,
    const float* __restrict__ Vr, float* __restrict__ g, float* __restrict__ rlog,
    const float* __restrict__ Xq, const float* __restrict__ Xk,
    const float* __restrict__ Xv,
    const ushort_t* __restrict__ WqT, const ushort_t* __restrict__ WkT,
    const ushort_t* __restrict__ WvT,
    ushort_t* __restrict__ qbf, ushort_t* __restrict__ kbf,
    ushort_t* __restrict__ vTbf,
    const int* __restrict__ win, uint_t* __restrict__ ent,
    int* __restrict__ rowcnt)
{
  __shared__ __align__(16) char sm[SMEM_BYTES];
  int blk = blockIdx.x;
  if (blk < 1536) {
    dev_grlog(sm, blk, values, relations, dp, rel_mask, Age, Agr, Vr, g, rlog);
  } else if (blk < 3264) {
    int t = blk - 1536;
    dev_mmqkv(sm, t % 96, (t/96) % 6, t/576, Xq, Xk, Xv, WqT, WkT, WvT,
              qbf, kbf, vTbf);
  } else {
    int t = blk - 3264;
    dev_collect(sm, t % 12, (t/12) % 12, t/144, win, ent, rowcnt);
  }
}

// mega2: [0,288) aw | [288,4896) attn3
__global__ __launch_bounds__(256) void k_mega2(
    const ushort_t* __restrict__ qbf, const ushort_t* __restrict__ kbf,
    const ushort_t* __restrict__ vTbf,
    const ull_t* __restrict__ mbits, const int* __restrict__ rowcnt,
    const uint_t* __restrict__ ent,
    const float* __restrict__ g, const float* __restrict__ rlog,
    ushort_t* __restrict__ ctxbf,
    const int* __restrict__ mask, float* __restrict__ awp)
{
  __shared__ __align__(16) char sm[SMEM_BYTES];
  int blk = blockIdx.x;
  if (blk < 288) {
    dev_aw(sm, blk % 6, (blk/6) % 3, blk/18, qbf, kbf, awp, mask, 1.f/12.f);
  } else {
    dev_attn3(sm, blk - 288, qbf, kbf, vTbf, mbits, rowcnt, ent, g, rlog, ctxbf);
  }
}

// ---------------- final ctx @ Wo (64x128 tile, MODE 0 only)
__global__ __launch_bounds__(256) void k_mmout(
    const ushort_t* __restrict__ A, const ushort_t* __restrict__ BT,
    float* __restrict__ Cf)
{
  __shared__ ushort_t As[64*64];
  __shared__ ushort_t Bs[128*64];
  int m0 = blockIdx.x*64, n0 = blockIdx.y*128;
  int t = threadIdx.x;
  int wave = t >> 6, lane = t & 63;
  int wr = wave >> 1, wc = wave & 1;
  int lrow = lane & 15, lkg = lane >> 4;
  int sr = t >> 3, sc8 = t & 7;

  f32x4 acc[2][4];
  #pragma unroll
  for (int i = 0; i < 2; ++i)
    #pragma unroll
    for (int j = 0; j < 4; ++j) acc[i][j] = (f32x4)(0.f);

  for (int k0 = 0; k0 < Dm; k0 += 64) {
    __syncthreads();
    #pragma unroll
    for (int i = 0; i < 2; ++i) {
      int row = sr + i*32;
      uint4 va = *(const uint4*)(A + (size_t)(m0 + row)*Dm + k0 + sc8*8);
      *(uint4*)&As[row*64 + (sc8 ^ (row & 7))*8] = va;
    }
    #pragma unroll
    for (int i = 0; i < 4; ++i) {
      int row = sr + i*32;
      uint4 vb = *(const uint4*)(BT + (size_t)(n0 + row)*Dm + k0 + sc8*8);
      *(uint4*)&Bs[row*64 + (sc8 ^ (row & 7))*8] = vb;
    }
    __syncthreads();
    #pragma unroll
    for (int kk = 0; kk < 2; ++kk) {
      bf16x8 aF[2], bF[4];
      int chunk = kk*4 + lkg;
      #pragma unroll
      for (int mi = 0; mi < 2; ++mi) {
        int arow = wr*32 + mi*16 + lrow;
        aF[mi] = *(const bf16x8*)&As[arow*64 + ((chunk ^ (arow & 7)) << 3)];
      }
      #pragma unroll
      for (int ni = 0; ni < 4; ++ni) {
        int brow = wc*64 + ni*16 + lrow;
        bF[ni] = *(const bf16x8*)&Bs[brow*64 + ((chunk ^ (brow & 7)) << 3)];
      }
      #pragma unroll
      for (int mi = 0; mi < 2; ++mi)
        #pragma unroll
        for (int ni = 0; ni < 4; ++ni)
          acc[mi][ni] = __builtin_amdgcn_mfma_f32_16x16x32_bf16(
              aF[mi], bF[ni], acc[mi][ni], 0, 0, 0);
    }
  }

  #pragma unroll
  for (int mi = 0; mi < 2; ++mi) {
    #pragma unroll
    for (int ni = 0; ni < 4; ++ni) {
      f32x4 a = acc[mi][ni];
      int grow = m0 + wr*32 + mi*16 + 4*lkg;
      int gcol = n0 + wc*64 + ni*16 + lrow;
      #pragma unroll
      for (int r = 0; r < 4; ++r)
        Cf[(size_t)(grow + r)*Dm + gcol] = a[r];
    }
  }
}

extern "C" void kernel_launch(void* const* d_in, const int* in_sizes, int n_in,
                              void* d_out, int out_size, void* d_ws, size_t ws_size,
                              hipStream_t stream) {
  const float* queries   = (const float*)d_in[0];
  const float* keys      = (const float*)d_in[1];
  const float* values    = (const float*)d_in[2];
  const float* relations = (const float*)d_in[3];
  const int*   dp_map    = (const int*)d_in[4];
  const int*   mask      = (const int*)d_in[5];
  const int*   rel_mask  = (const int*)d_in[6];
  const float* Wq  = (const float*)d_in[7];
  const float* Wk  = (const float*)d_in[8];
  const float* Wv  = (const float*)d_in[9];
  const float* Wo  = (const float*)d_in[10];
  const float* Wge = (const float*)d_in[11];
  const float* Wgr = (const float*)d_in[12];
  const float* Vr  = (const float*)d_in[13];
  const float* Vg  = (const float*)d_in[14];

  float* ws = (float*)d_ws;
  const size_t SZ   = (size_t)Bn*Lq*Dm;      // 4718592
  const size_t WINS = (size_t)Bn*Lq*Lq;      // 2359296
  const size_t GSZ  = (size_t)Bn*Hn*Lq;      // 73728
  const size_t ROWS = (size_t)Bn*Lq;         // 6144

  int*   win  = (int*)ws;
  float* g    = ws + WINS;
  float* rlog = g + GSZ;
  float* Age  = rlog + GSZ;
  float* Agr  = Age + (size_t)Hn*Dm;
  ull_t* mbits = (ull_t*)(Agr + (size_t)Hn*Dm);
  int*   rowcnt = (int*)(mbits + ROWS*6);
  uint_t* ent  = (uint_t*)(rowcnt + ROWS);
  ushort_t* p0 = (ushort_t*)(ent + ROWS*ECAP);
  ushort_t* qbf  = p0;
  ushort_t* kbf  = p0 + SZ;
  ushort_t* vTbf = p0 + 2*SZ;
  ushort_t* ctxbf= p0 + 3*SZ;
  ushort_t* WqT  = p0 + 4*SZ;
  ushort_t* WkT  = WqT + (size_t)Dm*Dm;
  ushort_t* WvT  = WkT + (size_t)Dm*Dm;
  ushort_t* WoT  = WvT + (size_t)Dm*Dm;

  float* outp = (float*)d_out;               // (B,L,D)
  float* awp  = outp + SZ;                   // (B,L,L)

  hipMemsetAsync(win, 0xFF, WINS*sizeof(int), stream);
  hipMemsetAsync(rowcnt, 0, ROWS*sizeof(int), stream);
  k_prep<<<3888, 256, 0, stream>>>(Wge, Wgr, Vg, Age, Agr,
                                   Wq, Wk, Wv, Wo, WqT, WkT, WvT, WoT,
                                   dp_map, win, mask, mbits);
  k_mega1<<<5568, 256, 0, stream>>>(values, relations, dp_map, rel_mask,
                                    Age, Agr, Vr, g, rlog,
                                    queries, keys, values, WqT, WkT, WvT,
                                    qbf, kbf, vTbf, win, ent, rowcnt);
  k_mega2<<<4896, 256, 0, stream>>>(qbf, kbf, vTbf, mbits, rowcnt, ent,
                                    g, rlog, ctxbf, mask, awp);
  k_mmout<<<dim3(96, 6), 256, 0, stream>>>(ctxbf, WoT, outp);
}